// Round 1
// baseline (339.156 us; speedup 1.0000x reference)
//
#include <hip/hip_runtime.h>

// Problem constants (from reference setup_inputs)
#define BB   16
#define NN   8192
#define DD   128
#define MM   2048
#define TOPKK 512
#define TT   (BB*MM)     // 32768
#define BNN  (BB*NN)     // 131072

// ---------------- workspace layout (bytes) ----------------
// tail_agg   float[T*D]    @ 0          (16777216)
// new_hidden float[T*D]    @ 16777216   (16777216)
// agg_att    double[T]     @ 33554432   (262144)
// w          double[B*384] @ 33816576   (49152)
// cb         double[B]     @ 33865728   (128)
// idx        int[B*TOPK]   @ 33865856   (32768)

__global__ __launch_bounds__(256) void k_init(const float* __restrict__ tail_emd,
                                              float* __restrict__ tail_agg,
                                              float* __restrict__ new_hidden,
                                              double* __restrict__ agg_att) {
    int i = blockIdx.x * blockDim.x + threadIdx.x;
    if (i < TT * DD) {
        tail_agg[i]   = tail_emd[i];
        new_hidden[i] = 0.0f;
    }
    if (i < TT) agg_att[i] = 0.0;
}

// Per-batch precompute: query_b, alpha_b, w_b = Wa @ alpha_b, c_b.
// One block (128 threads) per batch. All f64 for accuracy.
__global__ __launch_bounds__(128) void k_prep(const float* __restrict__ q_head,
                                              const float* __restrict__ q_rel,
                                              const float* __restrict__ q_time,
                                              const float* __restrict__ Wq,
                                              const float* __restrict__ bq,
                                              const float* __restrict__ Wa,
                                              const float* __restrict__ ba,
                                              const float* __restrict__ Watt,
                                              const float* __restrict__ batt,
                                              double* __restrict__ w_out,   // B*384
                                              double* __restrict__ c_out) { // B
    int b = blockIdx.x;
    int d = threadIdx.x; // 0..127
    __shared__ double alpha_s[DD];
    __shared__ double kpart[DD];

    // query_b[d] = concat(q_head,q_rel,q_time)_b @ Wq[:,d] + bq[d]
    double acc = (double)bq[d];
    for (int k = 0; k < DD; ++k) acc += (double)q_head[b*DD + k] * (double)Wq[(k      )*DD + d];
    for (int k = 0; k < DD; ++k) acc += (double)q_rel [b*DD + k] * (double)Wq[(DD + k )*DD + d];
    for (int k = 0; k < DD; ++k) acc += (double)q_time[b*DD + k] * (double)Wq[(2*DD+k )*DD + d];

    double W1 = (double)Watt[d];
    double W2 = (double)Watt[DD + d];
    double W3 = (double)Watt[2*DD + d];
    double a  = W1 * acc - W2 + W3;
    alpha_s[d] = a;
    kpart[d]   = acc * (W2 + W3) + (double)ba[d] * a;
    __syncthreads();

    // w_b[k] = sum_d Wa[k,d] * alpha[d]
    for (int kk = d; kk < 3*DD; kk += DD) {
        double s = 0.0;
        for (int dd = 0; dd < DD; ++dd) s += (double)Wa[kk*DD + dd] * alpha_s[dd];
        w_out[b*3*DD + kk] = s;
    }
    if (d == 0) {
        double K = (double)batt[0];
        for (int dd = 0; dd < DD; ++dd) K += kpart[dd];
        c_out[b] = K;
    }
}

// Main streaming kernel: one wave (64 lanes) per row of B*N.
__global__ __launch_bounds__(256) void k_main(const float* __restrict__ r_n,
                                              const float* __restrict__ t_n,
                                              const float* __restrict__ tm_n,
                                              const float* __restrict__ hidden,
                                              const float* __restrict__ q_head,
                                              const float* __restrict__ Wrule,
                                              const float* __restrict__ brule,
                                              const int* __restrict__ tail_index,
                                              const double* __restrict__ w_all,
                                              const double* __restrict__ c_all,
                                              float* __restrict__ tail_agg,
                                              float* __restrict__ new_hidden,
                                              double* __restrict__ agg_att) {
    const int wave = threadIdx.x >> 6;
    const int lane = threadIdx.x & 63;
    const long long row = (long long)blockIdx.x * 4 + wave;
    const int b  = (int)(row >> 13);        // row / N
    const long long base = row * DD;
    const int d0 = 2 * lane;

    float2 rv = *(const float2*)(r_n    + base + d0);
    float2 tv = *(const float2*)(t_n    + base + d0);
    float2 mv = *(const float2*)(tm_n   + base + d0);
    float2 hv = *(const float2*)(hidden + base + d0);

    const double* w = w_all + b * 3 * DD;
    double z1 = (double)rv.x * w[d0]          + (double)rv.y * w[d0 + 1]
              + (double)tv.x * w[DD + d0]     + (double)tv.y * w[DD + d0 + 1]
              + (double)mv.x * w[2*DD + d0]   + (double)mv.y * w[2*DD + d0 + 1];
    double z2 = (double)hv.x * (double)Wrule[d0] + (double)hv.y * (double)Wrule[d0 + 1];

    #pragma unroll
    for (int o = 32; o > 0; o >>= 1) {
        z1 += __shfl_xor(z1, o);
        z2 += __shfl_xor(z2, o);
    }
    z1 += c_all[b];
    z2 += (double)brule[0];
    double att1 = 1.0 / (1.0 + exp(-z1));
    double att2 = 1.0 / (1.0 + exp(-z2));
    double attd = 0.5 * (att1 + att2);
    float  att  = (float)attd;

    int t = tail_index[row];
    float2 qh = *(const float2*)(q_head + b*DD + d0);
    float m0 = att * (qh.x + rv.x + mv.x);
    float m1 = att * (qh.y + rv.y + mv.y);

    float* ta = tail_agg + (long long)t * DD + d0;
    unsafeAtomicAdd(ta,     m0);
    unsafeAtomicAdd(ta + 1, m1);
    float* nh = new_hidden + (long long)t * DD + d0;
    unsafeAtomicAdd(nh,     hv.x);
    unsafeAtomicAdd(nh + 1, hv.y);
    if (lane == 0) unsafeAtomicAdd(&agg_att[t], attd);
}

// Per-batch exact top-k: full bitonic sort of M=2048 (value desc, index asc),
// matching jax.lax.top_k semantics. One block per batch.
__global__ __launch_bounds__(512) void k_topk(const double* __restrict__ agg_att,
                                              const int* __restrict__ tail_nodes,
                                              int* __restrict__ idx_out,
                                              float* __restrict__ out_nodes) {
    int b = blockIdx.x;
    __shared__ double v[MM];
    __shared__ int    id[MM];
    for (int i = threadIdx.x; i < MM; i += blockDim.x) {
        v[i]  = agg_att[b*MM + i];
        id[i] = i;
    }
    __syncthreads();
    for (int k = 2; k <= MM; k <<= 1) {
        for (int j = k >> 1; j > 0; j >>= 1) {
            for (int i = threadIdx.x; i < MM; i += blockDim.x) {
                int ixj = i ^ j;
                if (ixj > i) {
                    double va = v[i], vb = v[ixj];
                    int    ia = id[i], ib = id[ixj];
                    bool aBeforeB = (va > vb) || (va == vb && ia < ib);
                    bool wantBefore = ((i & k) == 0);
                    if (wantBefore != aBeforeB) {
                        v[i] = vb; v[ixj] = va;
                        id[i] = ib; id[ixj] = ia;
                    }
                }
            }
            __syncthreads();
        }
    }
    for (int r = threadIdx.x; r < TOPKK; r += blockDim.x) {
        int t = b * MM + id[r];
        idx_out[b*TOPKK + r] = t;
        out_nodes[(b*TOPKK + r)*2 + 0] = (float)tail_nodes[t*3 + 1];
        out_nodes[(b*TOPKK + r)*2 + 1] = (float)tail_nodes[t*3 + 2];
    }
}

// Epilogue: emd = tail_agg[idx] @ Wout + bout ; hid = new_hidden[idx]
__global__ __launch_bounds__(128) void k_out(const float* __restrict__ tail_agg,
                                             const float* __restrict__ new_hidden,
                                             const float* __restrict__ Wout,
                                             const float* __restrict__ bout,
                                             const int* __restrict__ idx_ws,
                                             float* __restrict__ out_emd,
                                             float* __restrict__ out_hid) {
    int pair = blockIdx.x;           // b*TOPK + r
    int c = threadIdx.x;
    int t = idx_ws[pair];
    __shared__ float a_s[DD];
    a_s[c] = tail_agg[(long long)t * DD + c];
    __syncthreads();
    float acc = bout[c];
    #pragma unroll
    for (int d = 0; d < DD; ++d) acc = fmaf(a_s[d], Wout[d*DD + c], acc);
    out_emd[(long long)pair * DD + c] = acc;
    out_hid[(long long)pair * DD + c] = new_hidden[(long long)t * DD + c];
}

extern "C" void kernel_launch(void* const* d_in, const int* in_sizes, int n_in,
                              void* d_out, int out_size, void* d_ws, size_t ws_size,
                              hipStream_t stream) {
    const float* q_head   = (const float*)d_in[0];
    const float* q_rel    = (const float*)d_in[1];
    const float* q_time   = (const float*)d_in[2];
    const float* r_n      = (const float*)d_in[3];
    const float* t_n      = (const float*)d_in[4];
    const float* tm_n     = (const float*)d_in[5];
    const float* hidden   = (const float*)d_in[6];
    const float* tail_emd = (const float*)d_in[7];
    const int*   tail_index = (const int*)d_in[8];
    const int*   tail_nodes = (const int*)d_in[9];
    const float* Wq   = (const float*)d_in[10];
    const float* bq   = (const float*)d_in[11];
    const float* Wa   = (const float*)d_in[12];
    const float* ba   = (const float*)d_in[13];
    const float* Watt = (const float*)d_in[14];
    const float* batt = (const float*)d_in[15];
    const float* Wrule = (const float*)d_in[16];
    const float* brule = (const float*)d_in[17];
    const float* Wout = (const float*)d_in[18];
    const float* bout = (const float*)d_in[19];

    char* ws = (char*)d_ws;
    float*  tail_agg   = (float*) (ws + 0);
    float*  new_hidden = (float*) (ws + 16777216);
    double* agg_att    = (double*)(ws + 33554432);
    double* w_all      = (double*)(ws + 33816576);
    double* c_all      = (double*)(ws + 33865728);
    int*    idx_ws     = (int*)   (ws + 33865856);

    float* out       = (float*)d_out;
    float* out_nodes = out;                      // B*TOPK*2
    float* out_emd   = out + BB*TOPKK*2;         // B*TOPK*D
    float* out_hid   = out_emd + BB*TOPKK*DD;    // B*TOPK*D

    hipLaunchKernelGGL(k_init, dim3((TT*DD + 255)/256), dim3(256), 0, stream,
                       tail_emd, tail_agg, new_hidden, agg_att);
    hipLaunchKernelGGL(k_prep, dim3(BB), dim3(DD), 0, stream,
                       q_head, q_rel, q_time, Wq, bq, Wa, ba, Watt, batt,
                       w_all, c_all);
    hipLaunchKernelGGL(k_main, dim3(BNN/4), dim3(256), 0, stream,
                       r_n, t_n, tm_n, hidden, q_head, Wrule, brule,
                       tail_index, w_all, c_all, tail_agg, new_hidden, agg_att);
    hipLaunchKernelGGL(k_topk, dim3(BB), dim3(512), 0, stream,
                       agg_att, tail_nodes, idx_ws, out_nodes);
    hipLaunchKernelGGL(k_out, dim3(BB*TOPKK), dim3(DD), 0, stream,
                       tail_agg, new_hidden, Wout, bout, idx_ws,
                       out_emd, out_hid);
}

// Round 2
// 174.165 us; speedup vs baseline: 1.9473x; 1.9473x over previous
//
#include <hip/hip_runtime.h>

// Problem constants (from reference setup_inputs)
#define BB    16
#define NN    8192
#define DD    128
#define MM    2048
#define TOPKK 512
#define TT    (BB*MM)     // 32768
#define BNN   (BB*NN)     // 131072

// ---------------- workspace layout (bytes) ----------------
#define WS_TAIL_AGG   0            // float[T*D]   16777216
#define WS_NEW_HID    16777216     // float[T*D]   16777216
#define WS_AGG_ATT    33554432     // double[T]    262144
#define WS_W          33816576     // double[B*384] 49152
#define WS_C          33865728     // double[B]    128
#define WS_IDX        33865856     // int[B*TOPK]  32768
#define WS_COUNTS     33898624     // int[T]       131072
#define WS_OFFSETS    34029696     // int[T+1]     131080
#define WS_CURSOR     34160776     // int[T]       131072
#define WS_LIST       34291848     // int[BNN]     524288
#define WS_BLKSUM     34816136     // int[32]      128

__global__ __launch_bounds__(1024) void k_zero(int* __restrict__ counts) {
    int i = blockIdx.x * 1024 + threadIdx.x;
    if (i < TT) counts[i] = 0;
}

// Per-batch precompute: query_b, alpha_b, w_b = Wa @ alpha_b, c_b. All f64.
__global__ __launch_bounds__(128) void k_prep(const float* __restrict__ q_head,
                                              const float* __restrict__ q_rel,
                                              const float* __restrict__ q_time,
                                              const float* __restrict__ Wq,
                                              const float* __restrict__ bq,
                                              const float* __restrict__ Wa,
                                              const float* __restrict__ ba,
                                              const float* __restrict__ Watt,
                                              const float* __restrict__ batt,
                                              double* __restrict__ w_out,   // B*384
                                              double* __restrict__ c_out) { // B
    int b = blockIdx.x;
    int d = threadIdx.x; // 0..127
    __shared__ double x_s[3*DD];
    __shared__ double alpha_s[DD];
    __shared__ double kpart[DD];
    x_s[d]        = (double)q_head[b*DD + d];
    x_s[DD + d]   = (double)q_rel [b*DD + d];
    x_s[2*DD + d] = (double)q_time[b*DD + d];
    __syncthreads();

    double acc = (double)bq[d];
    for (int k = 0; k < 3*DD; ++k) acc += x_s[k] * (double)Wq[k*DD + d];

    double W1 = (double)Watt[d];
    double W2 = (double)Watt[DD + d];
    double W3 = (double)Watt[2*DD + d];
    double a  = W1 * acc - W2 + W3;
    alpha_s[d] = a;
    kpart[d]   = acc * (W2 + W3) + (double)ba[d] * a;
    __syncthreads();

    for (int kk = d; kk < 3*DD; kk += DD) {
        double s = 0.0;
        for (int dd = 0; dd < DD; ++dd) s += (double)Wa[kk*DD + dd] * alpha_s[dd];
        w_out[b*3*DD + kk] = s;
    }
    if (d == 0) {
        double K = (double)batt[0];
        for (int dd = 0; dd < DD; ++dd) K += kpart[dd];
        c_out[b] = K;
    }
}

__global__ __launch_bounds__(256) void k_count(const int* __restrict__ tail_index,
                                               int* __restrict__ counts) {
    int i = blockIdx.x * 256 + threadIdx.x;
    if (i < BNN) atomicAdd(&counts[tail_index[i]], 1);
}

// Block-level exclusive scan of counts (32 blocks x 1024 covering T=32768)
__global__ __launch_bounds__(1024) void k_scanA(const int* __restrict__ counts,
                                                int* __restrict__ offsets,
                                                int* __restrict__ blkSum) {
    __shared__ int s[1024];
    int tid = threadIdx.x;
    int g = blockIdx.x * 1024 + tid;
    int v = counts[g];
    s[tid] = v;
    __syncthreads();
    for (int off = 1; off < 1024; off <<= 1) {
        int t = (tid >= off) ? s[tid - off] : 0;
        __syncthreads();
        s[tid] += t;
        __syncthreads();
    }
    offsets[g] = s[tid] - v;                 // block-local exclusive
    if (tid == 1023) blkSum[blockIdx.x] = s[tid];
}

__global__ __launch_bounds__(1024) void k_scanB(int* __restrict__ offsets,
                                                int* __restrict__ cursor,
                                                const int* __restrict__ blkSum) {
    int b = blockIdx.x, tid = threadIdx.x;
    int base = 0;
    for (int j = 0; j < b; ++j) base += blkSum[j];
    int g = b * 1024 + tid;
    int e = offsets[g] + base;
    offsets[g] = e;
    cursor[g]  = e;
    if (b == 31 && tid == 1023) offsets[TT] = base + blkSum[31];
}

__global__ __launch_bounds__(256) void k_fill(const int* __restrict__ tail_index,
                                              int* __restrict__ cursor,
                                              int* __restrict__ list) {
    int i = blockIdx.x * 256 + threadIdx.x;
    if (i < BNN) {
        int t = tail_index[i];
        int p = atomicAdd(&cursor[t], 1);
        list[p] = i;
    }
}

// Gather-aggregate: one wave (64 lanes) per segment t. No f32 atomics.
__global__ __launch_bounds__(256) void k_agg(const float* __restrict__ r_n,
                                             const float* __restrict__ t_n,
                                             const float* __restrict__ tm_n,
                                             const float* __restrict__ hidden,
                                             const float* __restrict__ q_head,
                                             const float* __restrict__ tail_emd,
                                             const float* __restrict__ Wrule,
                                             const float* __restrict__ brule,
                                             const int* __restrict__ offsets,
                                             const int* __restrict__ list,
                                             const double* __restrict__ w_all,
                                             const double* __restrict__ c_all,
                                             float* __restrict__ tail_agg,
                                             float* __restrict__ new_hidden,
                                             double* __restrict__ agg_att) {
    const int wave = threadIdx.x >> 6;
    const int lane = threadIdx.x & 63;
    const int t = blockIdx.x * 4 + wave;
    const int b = t >> 11;               // t / M
    const int d0 = 2 * lane;

    const double* w = w_all + b * 3 * DD;
    double2 w0 = *(const double2*)(w + d0);
    double2 w1 = *(const double2*)(w + DD + d0);
    double2 w2 = *(const double2*)(w + 2*DD + d0);
    float2  wr = *(const float2*)(Wrule + d0);
    float2  qh = *(const float2*)(q_head + b*DD + d0);
    const double cb = c_all[b];
    const double br = (double)brule[0];

    const int start = offsets[t];
    const int end   = offsets[t + 1];

    float a0 = 0.f, a1 = 0.f, h0 = 0.f, h1 = 0.f;
    double asum = 0.0;

    for (int e = start; e < end; ++e) {
        int row = list[e];
        long long base = (long long)row * DD + d0;
        float2 rv = *(const float2*)(r_n    + base);
        float2 tv = *(const float2*)(t_n    + base);
        float2 mv = *(const float2*)(tm_n   + base);
        float2 hv = *(const float2*)(hidden + base);

        double z1 = (double)rv.x * w0.x + (double)rv.y * w0.y
                  + (double)tv.x * w1.x + (double)tv.y * w1.y
                  + (double)mv.x * w2.x + (double)mv.y * w2.y;
        double z2 = (double)hv.x * (double)wr.x + (double)hv.y * (double)wr.y;
        #pragma unroll
        for (int o = 32; o > 0; o >>= 1) {
            z1 += __shfl_xor(z1, o);
            z2 += __shfl_xor(z2, o);
        }
        z1 += cb;
        z2 += br;
        double att1 = 1.0 / (1.0 + exp(-z1));
        double att2 = 1.0 / (1.0 + exp(-z2));
        double attd = 0.5 * (att1 + att2);
        float  att  = (float)attd;

        a0 += att * (qh.x + rv.x + mv.x);
        a1 += att * (qh.y + rv.y + mv.y);
        h0 += hv.x;
        h1 += hv.y;
        asum += attd;
    }

    long long o = (long long)t * DD + d0;
    float2 te = *(const float2*)(tail_emd + o);
    float2 ta; ta.x = te.x + a0; ta.y = te.y + a1;
    *(float2*)(tail_agg + o) = ta;
    float2 nh; nh.x = h0; nh.y = h1;
    *(float2*)(new_hidden + o) = nh;
    if (lane == 0) agg_att[t] = asum;
}

// Per-batch exact top-k: bitonic sort of M=2048 (value desc, index asc).
__global__ __launch_bounds__(1024) void k_topk(const double* __restrict__ agg_att,
                                               const int* __restrict__ tail_nodes,
                                               int* __restrict__ idx_out,
                                               float* __restrict__ out_nodes) {
    int b = blockIdx.x;
    __shared__ double v[MM];
    __shared__ int    id[MM];
    for (int i = threadIdx.x; i < MM; i += blockDim.x) {
        v[i]  = agg_att[b*MM + i];
        id[i] = i;
    }
    __syncthreads();
    for (int k = 2; k <= MM; k <<= 1) {
        for (int j = k >> 1; j > 0; j >>= 1) {
            for (int i = threadIdx.x; i < MM; i += blockDim.x) {
                int ixj = i ^ j;
                if (ixj > i) {
                    double va = v[i], vb = v[ixj];
                    int    ia = id[i], ib = id[ixj];
                    bool aBeforeB = (va > vb) || (va == vb && ia < ib);
                    bool wantBefore = ((i & k) == 0);
                    if (wantBefore != aBeforeB) {
                        v[i] = vb; v[ixj] = va;
                        id[i] = ib; id[ixj] = ia;
                    }
                }
            }
            __syncthreads();
        }
    }
    for (int r = threadIdx.x; r < TOPKK; r += blockDim.x) {
        int t = b * MM + id[r];
        idx_out[b*TOPKK + r] = t;
        out_nodes[(b*TOPKK + r)*2 + 0] = (float)tail_nodes[t*3 + 1];
        out_nodes[(b*TOPKK + r)*2 + 1] = (float)tail_nodes[t*3 + 2];
    }
}

// Epilogue: emd = tail_agg[idx] @ Wout + bout ; hid = new_hidden[idx]
// 8 rows per block to amortize Wout reads.
#define ROWS_PER_BLK 8
__global__ __launch_bounds__(128) void k_out(const float* __restrict__ tail_agg,
                                             const float* __restrict__ new_hidden,
                                             const float* __restrict__ Wout,
                                             const float* __restrict__ bout,
                                             const int* __restrict__ idx_ws,
                                             float* __restrict__ out_emd,
                                             float* __restrict__ out_hid) {
    int c = threadIdx.x;
    int pair0 = blockIdx.x * ROWS_PER_BLK;
    __shared__ float a_s[ROWS_PER_BLK][DD];
    int ts[ROWS_PER_BLK];
    #pragma unroll
    for (int j = 0; j < ROWS_PER_BLK; ++j) {
        ts[j] = idx_ws[pair0 + j];
        a_s[j][c] = tail_agg[(long long)ts[j] * DD + c];
    }
    __syncthreads();
    float acc[ROWS_PER_BLK];
    float bc = bout[c];
    #pragma unroll
    for (int j = 0; j < ROWS_PER_BLK; ++j) acc[j] = bc;
    for (int d = 0; d < DD; ++d) {
        float wv = Wout[d*DD + c];
        #pragma unroll
        for (int j = 0; j < ROWS_PER_BLK; ++j)
            acc[j] = fmaf(a_s[j][d], wv, acc[j]);
    }
    #pragma unroll
    for (int j = 0; j < ROWS_PER_BLK; ++j) {
        long long p = (long long)(pair0 + j) * DD + c;
        out_emd[p] = acc[j];
        out_hid[p] = new_hidden[(long long)ts[j] * DD + c];
    }
}

extern "C" void kernel_launch(void* const* d_in, const int* in_sizes, int n_in,
                              void* d_out, int out_size, void* d_ws, size_t ws_size,
                              hipStream_t stream) {
    const float* q_head   = (const float*)d_in[0];
    const float* q_rel    = (const float*)d_in[1];
    const float* q_time   = (const float*)d_in[2];
    const float* r_n      = (const float*)d_in[3];
    const float* t_n      = (const float*)d_in[4];
    const float* tm_n     = (const float*)d_in[5];
    const float* hidden   = (const float*)d_in[6];
    const float* tail_emd = (const float*)d_in[7];
    const int*   tail_index = (const int*)d_in[8];
    const int*   tail_nodes = (const int*)d_in[9];
    const float* Wq   = (const float*)d_in[10];
    const float* bq   = (const float*)d_in[11];
    const float* Wa   = (const float*)d_in[12];
    const float* ba   = (const float*)d_in[13];
    const float* Watt = (const float*)d_in[14];
    const float* batt = (const float*)d_in[15];
    const float* Wrule = (const float*)d_in[16];
    const float* brule = (const float*)d_in[17];
    const float* Wout = (const float*)d_in[18];
    const float* bout = (const float*)d_in[19];

    char* ws = (char*)d_ws;
    float*  tail_agg   = (float*) (ws + WS_TAIL_AGG);
    float*  new_hidden = (float*) (ws + WS_NEW_HID);
    double* agg_att    = (double*)(ws + WS_AGG_ATT);
    double* w_all      = (double*)(ws + WS_W);
    double* c_all      = (double*)(ws + WS_C);
    int*    idx_ws     = (int*)   (ws + WS_IDX);
    int*    counts     = (int*)   (ws + WS_COUNTS);
    int*    offsets    = (int*)   (ws + WS_OFFSETS);
    int*    cursor     = (int*)   (ws + WS_CURSOR);
    int*    list       = (int*)   (ws + WS_LIST);
    int*    blkSum     = (int*)   (ws + WS_BLKSUM);

    float* out       = (float*)d_out;
    float* out_nodes = out;                      // B*TOPK*2
    float* out_emd   = out + BB*TOPKK*2;         // B*TOPK*D
    float* out_hid   = out_emd + BB*TOPKK*DD;    // B*TOPK*D

    hipLaunchKernelGGL(k_zero, dim3(TT/1024), dim3(1024), 0, stream, counts);
    hipLaunchKernelGGL(k_prep, dim3(BB), dim3(DD), 0, stream,
                       q_head, q_rel, q_time, Wq, bq, Wa, ba, Watt, batt,
                       w_all, c_all);
    hipLaunchKernelGGL(k_count, dim3(BNN/256), dim3(256), 0, stream,
                       tail_index, counts);
    hipLaunchKernelGGL(k_scanA, dim3(TT/1024), dim3(1024), 0, stream,
                       counts, offsets, blkSum);
    hipLaunchKernelGGL(k_scanB, dim3(TT/1024), dim3(1024), 0, stream,
                       offsets, cursor, blkSum);
    hipLaunchKernelGGL(k_fill, dim3(BNN/256), dim3(256), 0, stream,
                       tail_index, cursor, list);
    hipLaunchKernelGGL(k_agg, dim3(TT/4), dim3(256), 0, stream,
                       r_n, t_n, tm_n, hidden, q_head, tail_emd, Wrule, brule,
                       offsets, list, w_all, c_all,
                       tail_agg, new_hidden, agg_att);
    hipLaunchKernelGGL(k_topk, dim3(BB), dim3(1024), 0, stream,
                       agg_att, tail_nodes, idx_ws, out_nodes);
    hipLaunchKernelGGL(k_out, dim3(BB*TOPKK/ROWS_PER_BLK), dim3(DD), 0, stream,
                       tail_agg, new_hidden, Wout, bout, idx_ws,
                       out_emd, out_hid);
}